// Round 8
// baseline (604.259 us; speedup 1.0000x reference)
//
#include <hip/hip_runtime.h>
#include <hip/hip_cooperative_groups.h>

namespace cg = cooperative_groups;

#define NROWS 2048
#define DIM   1024
#define VOCAB 32000
#define BM 256
#define BN 256
#define BK 64
#define NRB (NROWS / BM)     // 8
#define NVB (VOCAB / BN)     // 125
#define NJOBS (NRB * NVB)    // 1000
#define NCB (VOCAB / 64)     // 500 col-blocks of 64
#define KSTEPS (DIM / BK)    // 16
#define NBLK 256
#define NTHR 512

typedef __attribute__((ext_vector_type(4))) float f32x4;
typedef __attribute__((ext_vector_type(8))) short bf16x8;
typedef unsigned int u32;

static __device__ inline unsigned short f2bf(float x) {
  union { float f; unsigned u; } c; c.f = x;
  unsigned r = c.u + 0x7fffu + ((c.u >> 16) & 1u);
  return (unsigned short)(r >> 16);
}

// One cooperative kernel, three grid-synced phases:
//  1. fp32->bf16 convert (cell+clsw), target logits, zero d_out
//  2. persistent 256x256 MFMA GEMM + fused per-64col logsumexp partials
//  3. per-row online combine + mean NLL atomicAdd
// GEMM staging is fragment-linear LDS (conflict-free), double-buffered,
// chunked by k-half: each phase waits vmcnt(4) (prev chunk landed, next
// chunk in flight - never drains to 0 until the job tail), one s_barrier
// per phase. Persistent g = bid + 256*j keeps rb = bid&7 constant per
// block (A panel L2-resident per XCD).
__global__ __launch_bounds__(NTHR, 2) void fused_kernel(
    const float* __restrict__ cell, const float* __restrict__ clsw,
    const int* __restrict__ labels, float* __restrict__ out,
    unsigned short* __restrict__ cellb, unsigned short* __restrict__ clswb,
    float* __restrict__ tlog, float* __restrict__ partials) {
  __shared__ unsigned short smem[65536];  // 128 KB: 2 bufs x (A 32KB | B 32KB)
  const int tid = threadIdx.x;
  const int wv = tid >> 6, lane = tid & 63;
  const int gtid = blockIdx.x * NTHR + tid;

  // ================= phase 1: zero-out, cvt, target logits =================
  if (gtid == 0) out[0] = 0.f;
  {
    const float4* src = (const float4*)cell;
    ushort4* dst = (ushort4*)cellb;
    for (int i = gtid; i < NROWS * DIM / 4; i += NBLK * NTHR) {
      float4 v = src[i];
      ushort4 h = {f2bf(v.x), f2bf(v.y), f2bf(v.z), f2bf(v.w)};
      dst[i] = h;
    }
    src = (const float4*)clsw;
    dst = (ushort4*)clswb;
    for (int i = gtid; i < VOCAB * DIM / 4; i += NBLK * NTHR) {
      float4 v = src[i];
      ushort4 h = {f2bf(v.x), f2bf(v.y), f2bf(v.z), f2bf(v.w)};
      dst[i] = h;
    }
  }
  {
    int row = blockIdx.x * 8 + wv;  // 2048 waves == 2048 rows, exact
    int lbl = labels[row];
    const float4* a = (const float4*)(cell + (size_t)row * DIM);
    const float4* b = (const float4*)(clsw + (size_t)lbl * DIM);
    float acc = 0.f;
#pragma unroll
    for (int q = 0; q < 4; ++q) {
      float4 av = a[q * 64 + lane];
      float4 bv = b[q * 64 + lane];
      acc += av.x * bv.x + av.y * bv.y + av.z * bv.z + av.w * bv.w;
    }
#pragma unroll
    for (int off = 32; off >= 1; off >>= 1) acc += __shfl_xor(acc, off);
    if (lane == 0) tlog[row] = acc;
  }
  __threadfence();
  cg::this_grid().sync();

  // ================= phase 2: persistent pipelined GEMM + LSE ==============
  {
    const int wr = wv >> 2, wc = wv & 3;    // 2x4 wave grid; wave owns 128x64
    const int lrow = lane & 15, lk = (lane >> 4) * 8;

    for (int g = blockIdx.x; g < NJOBS; g += NBLK) {
      const int rb = g & (NRB - 1);
      const int vb = g >> 3;
      const size_t Abase = (size_t)rb * BM * DIM;
      const size_t Bbase = (size_t)vb * BN * DIM;

      f32x4 acc[8][4];
#pragma unroll
      for (int m = 0; m < 8; ++m)
#pragma unroll
        for (int n = 0; n < 4; ++n) acc[m][n] = (f32x4){0.f, 0.f, 0.f, 0.f};

      // stage the k-half chunk ks of K-tile kt into buf (4 loads/wave)
      auto STAGE_CHUNK = [&](int kt, int buf, int ks) {
        unsigned short* As_ = smem + buf * 32768;
        unsigned short* Bs_ = As_ + 16384;
        const int kb = kt * BK + ks * 32 + lk;
#pragma unroll
        for (int q = 0; q < 2; ++q) {
          const int rt = wv * 2 + q;       // 16-row tile 0..15
          const int t = rt * 2 + ks;       // slot index
          const size_t off = (size_t)(rt * 16 + lrow) * DIM + kb;
          __builtin_amdgcn_global_load_lds(
              (const __attribute__((address_space(1))) u32*)(cellb + Abase + off),
              (__attribute__((address_space(3))) u32*)(As_ + t * 512), 16, 0, 0);
          __builtin_amdgcn_global_load_lds(
              (const __attribute__((address_space(1))) u32*)(clswb + Bbase + off),
              (__attribute__((address_space(3))) u32*)(Bs_ + t * 512), 16, 0, 0);
        }
      };

      STAGE_CHUNK(0, 0, 0);
      STAGE_CHUNK(0, 0, 1);

      for (int kt = 0; kt < KSTEPS; ++kt) {
        const int cur = kt & 1;
#pragma unroll
        for (int ks = 0; ks < 2; ++ks) {
          // wait: chunk(kt,ks) landed; chunk(kt,ks+1 or kt+1,ks-ish) in flight
          if (kt == KSTEPS - 1 && ks == 1)
            asm volatile("s_waitcnt vmcnt(0)" ::: "memory");
          else
            asm volatile("s_waitcnt vmcnt(4)" ::: "memory");
          __builtin_amdgcn_sched_barrier(0);
          __builtin_amdgcn_s_barrier();    // publish chunk to all waves
          __builtin_amdgcn_sched_barrier(0);

          const unsigned short* As_ = smem + cur * 32768;
          const unsigned short* Bs_ = As_ + 16384;
          bf16x8 b[4], a[8];
#pragma unroll
          for (int n = 0; n < 4; ++n)
            b[n] = *(const bf16x8*)(Bs_ + ((wc * 4 + n) * 2 + ks) * 512 + lane * 8);
#pragma unroll
          for (int m = 0; m < 8; ++m)
            a[m] = *(const bf16x8*)(As_ + ((wr * 8 + m) * 2 + ks) * 512 + lane * 8);
          if (kt < KSTEPS - 1) STAGE_CHUNK(kt + 1, cur ^ 1, ks);
          __builtin_amdgcn_s_setprio(1);
#pragma unroll
          for (int m = 0; m < 8; ++m)
#pragma unroll
            for (int n = 0; n < 4; ++n)
              acc[m][n] = __builtin_amdgcn_mfma_f32_16x16x32_bf16(a[m], b[n], acc[m][n], 0, 0, 0);
          __builtin_amdgcn_s_setprio(0);
        }
      }

      // fused epilogue: per-row (max, sum-exp) over this wave's 64-col slab.
      // C layout (m89): col = lane&15, row = (lane>>4)*4 + i.
#pragma unroll
      for (int m = 0; m < 8; ++m) {
#pragma unroll
        for (int i = 0; i < 4; ++i) {
          float mx = acc[m][0][i];
#pragma unroll
          for (int n = 1; n < 4; ++n) mx = fmaxf(mx, acc[m][n][i]);
          float s = 0.f;
#pragma unroll
          for (int n = 0; n < 4; ++n) s += __expf(acc[m][n][i] - mx);
#pragma unroll
          for (int off = 1; off <= 8; off <<= 1) {  // combine 16 col-lanes
            float om = __shfl_xor(mx, off);
            float os = __shfl_xor(s, off);
            float nm = fmaxf(mx, om);
            s = s * __expf(mx - nm) + os * __expf(om - nm);
            mx = nm;
          }
          if ((lane & 15) == 0) {
            int grow = rb * BM + wr * 128 + m * 16 + (lane >> 4) * 4 + i;
            int cb = vb * 4 + wc;
            *(float2*)(partials + ((size_t)grow * NCB + cb) * 2) = make_float2(mx, s);
          }
        }
      }
    }
  }
  __threadfence();
  cg::this_grid().sync();

  // ================= phase 3: per-row combine + mean NLL ===================
  {
    int row = blockIdx.x * 8 + wv;  // 2048 waves == 2048 rows
    const float2* p = (const float2*)(partials + (size_t)row * NCB * 2);
    float m = -1e30f, s = 0.f;
    for (int i = lane; i < NCB; i += 64) {
      float2 v = p[i];
      float nm = fmaxf(m, v.x);
      s = s * __expf(m - nm) + v.y * __expf(v.x - nm);
      m = nm;
    }
#pragma unroll
    for (int off = 1; off <= 32; off <<= 1) {
      float om = __shfl_xor(m, off);
      float os = __shfl_xor(s, off);
      float nm = fmaxf(m, om);
      s = s * __expf(m - nm) + os * __expf(om - nm);
      m = nm;
    }
    if (lane == 0)
      atomicAdd(out, (m + __logf(s) - tlog[row]) * (1.0f / NROWS));
  }
}

extern "C" void kernel_launch(void* const* d_in, const int* in_sizes, int n_in,
                              void* d_out, int out_size, void* d_ws, size_t ws_size,
                              hipStream_t stream) {
  const float* cell = (const float*)d_in[0];
  const float* clsw = (const float*)d_in[1];
  const int* labels = (const int*)d_in[2];
  float* out = (float*)d_out;

  unsigned short* cellb = (unsigned short*)d_ws;                       // 4 MB
  unsigned short* clswb = (unsigned short*)((char*)d_ws + 4194304);    // 65.5 MB
  float* tlog = (float*)((char*)d_ws + 69730304);                      // 8 KB
  float* partials = (float*)((char*)d_ws + 69738496);                  // 8.2 MB

  void* args[] = {&cell, &clsw, &labels, &out, &cellb, &clswb, &tlog, &partials};
  hipLaunchCooperativeKernel((void*)fused_kernel, dim3(NBLK), dim3(NTHR),
                             args, 0, stream);
}

// Round 11
// 383.592 us; speedup vs baseline: 1.5753x; 1.5753x over previous
//
#include <hip/hip_runtime.h>

#define NROWS 2048
#define DIM   1024
#define VOCAB 32000
#define BM 256
#define BN 256
#define BK 64
#define NRB (NROWS / BM)    // 8
#define NVB (VOCAB / BN)    // 125
#define NCB (VOCAB / 64)    // 500 col-blocks of 64
#define KSTEPS (DIM / BK)   // 16

typedef __attribute__((ext_vector_type(4))) float f32x4;
typedef __attribute__((ext_vector_type(8))) short bf16x8;
typedef unsigned int u32;
#define AS1 __attribute__((address_space(1)))
#define AS3 __attribute__((address_space(3)))
#define SB() __builtin_amdgcn_sched_barrier(0)

static __device__ inline unsigned short f2bf(float x) {
  union { float f; unsigned u; } c; c.f = x;
  unsigned r = c.u + 0x7fffu + ((c.u >> 16) & 1u);
  return (unsigned short)(r >> 16);
}

// ------------- prep: zero out, fp32->bf16 cvt (both), target logits --------
// 512 blocks x 256 thr = 131072 threads = 2048 waves (one per row for tgt).
__global__ __launch_bounds__(256) void prep_kernel(
    const float* __restrict__ cell, const float* __restrict__ clsw,
    const int* __restrict__ labels, float* __restrict__ out,
    unsigned short* __restrict__ cellb, unsigned short* __restrict__ clswb,
    float* __restrict__ tlog) {
  const int tid = threadIdx.x;
  const int wv = tid >> 6, lane = tid & 63;
  const int gtid = blockIdx.x * 256 + tid;
  if (gtid == 0) out[0] = 0.f;
  // target logit: one wave per row (gather rows in fp32)
  {
    int row = blockIdx.x * 4 + wv;
    int lbl = labels[row];
    const float4* a = (const float4*)(cell + (size_t)row * DIM);
    const float4* b = (const float4*)(clsw + (size_t)lbl * DIM);
    float acc = 0.f;
#pragma unroll
    for (int q = 0; q < 4; ++q) {
      float4 av = a[q * 64 + lane];
      float4 bv = b[q * 64 + lane];
      acc += av.x * bv.x + av.y * bv.y + av.z * bv.z + av.w * bv.w;
    }
#pragma unroll
    for (int off = 32; off >= 1; off >>= 1) acc += __shfl_xor(acc, off);
    if (lane == 0) tlog[row] = acc;
  }
  // streaming cvt: cell (4 iters), clsw (64 iters), fully coalesced
  {
    const float4* src = (const float4*)cell;
    ushort4* dst = (ushort4*)cellb;
#pragma unroll
    for (int j = 0; j < (NROWS * DIM / 4) / 131072; ++j) {
      int i = gtid + j * 131072;
      float4 v = src[i];
      ushort4 h = {f2bf(v.x), f2bf(v.y), f2bf(v.z), f2bf(v.w)};
      dst[i] = h;
    }
    src = (const float4*)clsw;
    dst = (ushort4*)clswb;
    for (int j = 0; j < (VOCAB * DIM / 4) / 131072; ++j) {
      int i = gtid + j * 131072;
      float4 v = src[i];
      ushort4 h = {f2bf(v.x), f2bf(v.y), f2bf(v.z), f2bf(v.w)};
      dst[i] = h;
    }
  }
}

// ------------- bf16 MFMA 256x256 GEMM, 8-phase ring pipeline + LSE ---------
// LDS = ring of 4 half-K buffers (32KB each: 16 A-slots + 16 B-slots of
// 1KB; slot = 64 lanes x 16B, fragment-linear => all ds_reads are contiguous
// 1024B wave reads, conflict-free; global_load_lds dest is wave-uniform).
// Half h = (t,ks) holds K-range t*64+ks*32..+32 of both panels.
// Per K-tile: 4 phases (ks,nh), each {ds_read 10|2, stage 2 gload_lds of
// half p+2, [counted vmcnt at 2nd phase of period], barrier, lgkmcnt(0),
// setprio(1), 16 MFMA, setprio(0), barrier}. vmcnt(4) retires half p+1,
// keeps half p+2 in flight (never drains mid-loop); vmcnt(0) only at p=30.
__global__ __launch_bounds__(512) void gemm_lse_kernel(
    const unsigned short* __restrict__ Ab, const unsigned short* __restrict__ Bb,
    float* __restrict__ partials) {
  __shared__ unsigned short smem[65536];  // 128 KB = 4 x 32 KB halves

  const int h = blockIdx.x;
  const int g = (h & 7) * (NRB * NVB / 8) + (h >> 3);  // XCD chunk swizzle
  const int rb = g & (NRB - 1);
  const int vb = g >> 3;
  const int tid = threadIdx.x;
  const int wv = tid >> 6, lane = tid & 63;
  const int wr = wv >> 2, wc = wv & 3;    // 2x4 wave grid; wave owns 128x64
  const int lrow = lane & 15, lk = (lane >> 4) * 8;

  const size_t Abase = (size_t)rb * BM * DIM;
  const size_t Bbase = (size_t)vb * BN * DIM;

  f32x4 acc[8][4];
#pragma unroll
  for (int m = 0; m < 8; ++m)
#pragma unroll
    for (int n = 0; n < 4; ++n) acc[m][n] = (f32x4){0.f, 0.f, 0.f, 0.f};

  // stage pair (A slot rt, B slot rt) of half-period p2 into ring slot p2&3
  auto STAGE_PAIR = [&](int p2, int pair) {
    unsigned short* H = smem + (p2 & 3) * 16384;
    const int rt = wv * 2 + pair;
    const size_t koff = (size_t)((p2 >> 1) * 64 + (p2 & 1) * 32 + lk);
    const size_t roff = (size_t)(rt * 16 + lrow) * DIM + koff;
    __builtin_amdgcn_global_load_lds((const AS1 u32*)(Ab + Abase + roff),
                                     (AS3 u32*)(H + rt * 512), 16, 0, 0);
    __builtin_amdgcn_global_load_lds((const AS1 u32*)(Bb + Bbase + roff),
                                     (AS3 u32*)(H + 8192 + rt * 512), 16, 0, 0);
  };

  // prologue: halves 0,1 (oldest 4 = half 0) -> wait half 0, publish
  STAGE_PAIR(0, 0); STAGE_PAIR(0, 1);
  STAGE_PAIR(1, 0); STAGE_PAIR(1, 1);
  asm volatile("s_waitcnt vmcnt(4)" ::: "memory");
  SB(); __builtin_amdgcn_s_barrier(); SB();

  for (int t = 0; t < KSTEPS; ++t) {
#pragma unroll
    for (int ks = 0; ks < 2; ++ks) {
      const int p = 2 * t + ks;
      const unsigned short* H = smem + (p & 3) * 16384;
      bf16x8 a[8], b0, b1;
      // ---- phase (ks,0): read a[0..7]+b[0..1], stage pair 0, MFMA n=0,1
#pragma unroll
      for (int m = 0; m < 8; ++m)
        a[m] = *(const bf16x8*)(H + (wr * 8 + m) * 512 + lane * 8);
      b0 = *(const bf16x8*)(H + 8192 + (wc * 4 + 0) * 512 + lane * 8);
      b1 = *(const bf16x8*)(H + 8192 + (wc * 4 + 1) * 512 + lane * 8);
      if (t < KSTEPS - 1) STAGE_PAIR(p + 2, 0);
      SB(); __builtin_amdgcn_s_barrier(); SB();
      asm volatile("s_waitcnt lgkmcnt(0)" ::: "memory");
      SB();
      __builtin_amdgcn_s_setprio(1);
#pragma unroll
      for (int m = 0; m < 8; ++m) {
        acc[m][0] = __builtin_amdgcn_mfma_f32_16x16x32_bf16(a[m], b0, acc[m][0], 0, 0, 0);
        acc[m][1] = __builtin_amdgcn_mfma_f32_16x16x32_bf16(a[m], b1, acc[m][1], 0, 0, 0);
      }
      __builtin_amdgcn_s_setprio(0);
      SB(); __builtin_amdgcn_s_barrier(); SB();
      // ---- phase (ks,1): read b[2..3], stage pair 1, counted wait, MFMA n=2,3
      b0 = *(const bf16x8*)(H + 8192 + (wc * 4 + 2) * 512 + lane * 8);
      b1 = *(const bf16x8*)(H + 8192 + (wc * 4 + 3) * 512 + lane * 8);
      if (t < KSTEPS - 1) STAGE_PAIR(p + 2, 1);
      if (t < KSTEPS - 1)
        asm volatile("s_waitcnt vmcnt(4)" ::: "memory");   // retire half p+1
      else if (ks == 0)
        asm volatile("s_waitcnt vmcnt(0)" ::: "memory");   // retire last half
      SB(); __builtin_amdgcn_s_barrier(); SB();
      asm volatile("s_waitcnt lgkmcnt(0)" ::: "memory");
      SB();
      __builtin_amdgcn_s_setprio(1);
#pragma unroll
      for (int m = 0; m < 8; ++m) {
        acc[m][2] = __builtin_amdgcn_mfma_f32_16x16x32_bf16(a[m], b0, acc[m][2], 0, 0, 0);
        acc[m][3] = __builtin_amdgcn_mfma_f32_16x16x32_bf16(a[m], b1, acc[m][3], 0, 0, 0);
      }
      __builtin_amdgcn_s_setprio(0);
      SB(); __builtin_amdgcn_s_barrier(); SB();
    }
  }

  // fused epilogue: per-row (max, sum-exp) over this wave's 64-col slab.
  // C layout (m89): col = lane&15, row = (lane>>4)*4 + i.
#pragma unroll
  for (int m = 0; m < 8; ++m) {
#pragma unroll
    for (int i = 0; i < 4; ++i) {
      float mx = acc[m][0][i];
#pragma unroll
      for (int n = 1; n < 4; ++n) mx = fmaxf(mx, acc[m][n][i]);
      float s = 0.f;
#pragma unroll
      for (int n = 0; n < 4; ++n) s += __expf(acc[m][n][i] - mx);
#pragma unroll
      for (int off = 1; off <= 8; off <<= 1) {  // combine 16 col-lanes
        float om = __shfl_xor(mx, off);
        float os = __shfl_xor(s, off);
        float nm = fmaxf(mx, om);
        s = s * __expf(mx - nm) + os * __expf(om - nm);
        mx = nm;
      }
      if ((lane & 15) == 0) {
        int grow = rb * BM + wr * 128 + m * 16 + (lane >> 4) * 4 + i;
        int cb = vb * 4 + wc;
        *(float2*)(partials + ((size_t)grow * NCB + cb) * 2) = make_float2(mx, s);
      }
    }
  }
}

// ---------------- per-row combine + mean NLL -------------------------------
__global__ __launch_bounds__(256) void reduce_kernel(
    const float* __restrict__ partials, const float* __restrict__ tlog,
    float* __restrict__ out) {
  int wv = threadIdx.x >> 6, lane = threadIdx.x & 63;
  int row = blockIdx.x * 4 + wv;
  const float2* p = (const float2*)(partials + (size_t)row * NCB * 2);
  float m = -1e30f, s = 0.f;
  for (int i = lane; i < NCB; i += 64) {
    float2 v = p[i];
    float nm = fmaxf(m, v.x);
    s = s * __expf(m - nm) + v.y * __expf(v.x - nm);
    m = nm;
  }
#pragma unroll
  for (int off = 1; off <= 32; off <<= 1) {
    float om = __shfl_xor(m, off);
    float os = __shfl_xor(s, off);
    float nm = fmaxf(m, om);
    s = s * __expf(m - nm) + os * __expf(om - nm);
    m = nm;
  }
  float loss = m + __logf(s) - tlog[row];
  __shared__ float red[4];
  if (lane == 0) red[wv] = loss;
  __syncthreads();
  if (threadIdx.x == 0)
    atomicAdd(out, (red[0] + red[1] + red[2] + red[3]) * (1.0f / NROWS));
}

extern "C" void kernel_launch(void* const* d_in, const int* in_sizes, int n_in,
                              void* d_out, int out_size, void* d_ws, size_t ws_size,
                              hipStream_t stream) {
  const float* cell = (const float*)d_in[0];
  const float* clsw = (const float*)d_in[1];
  const int* labels = (const int*)d_in[2];
  float* out = (float*)d_out;

  unsigned short* cellb = (unsigned short*)d_ws;                       // 4 MB
  unsigned short* clswb = (unsigned short*)((char*)d_ws + 4194304);    // 65.5 MB
  float* tlog = (float*)((char*)d_ws + 69730304);                      // 8 KB
  float* partials = (float*)((char*)d_ws + 69738496);                  // 8.2 MB

  prep_kernel<<<512, 256, 0, stream>>>(cell, clsw, labels, out, cellb, clswb, tlog);
  gemm_lse_kernel<<<NRB * NVB, 512, 0, stream>>>(cellb, clswb, partials);
  reduce_kernel<<<NROWS / 4, 256, 0, stream>>>(partials, tlog, out);
}